// Round 4
// baseline (1383.368 us; speedup 1.0000x reference)
//
#include <hip/hip_runtime.h>

#define N_NODES 100000
#define FDIM 64

// ---------------- Kernel 1: SpMM via fp32 HW atomics ----------------
// 16 lanes per edge; lane l handles features [4l, 4l+4).
// Reads x[col] as float4 (coalesced 256B per edge), scatter-adds into out[row].
__global__ __launch_bounds__(256) void spmm_atomic(
    const float* __restrict__ x,
    const int* __restrict__ erow,
    const int* __restrict__ ecol,
    const float* __restrict__ eval,
    float* __restrict__ out,
    int n_edges)
{
    int tid = blockIdx.x * 256 + threadIdx.x;
    int e = tid >> 4;
    int l = tid & 15;
    if (e >= n_edges) return;

    int row = erow[e];
    int col = ecol[e];
    float v = eval[e];

    const float4 xv = *reinterpret_cast<const float4*>(x + (size_t)col * FDIM + l * 4);
    float* dst = out + (size_t)row * FDIM + l * 4;
    unsafeAtomicAdd(dst + 0, v * xv.x);
    unsafeAtomicAdd(dst + 1, v * xv.y);
    unsafeAtomicAdd(dst + 2, v * xv.z);
    unsafeAtomicAdd(dst + 3, v * xv.w);
}

// ---------------- Kernel 2: in-place  out = normalize(support @ W + b) ----------------
// Block = 256 threads = 4 waves. Each wave handles 4 consecutive rows:
// sub = lane/16 picks the row, l = lane%16 picks output features [4l,4l+4).
__global__ __launch_bounds__(256) void gemm_norm(
    float* __restrict__ io,              // [N,64] support in, normalized out (in-place)
    const float* __restrict__ W,         // [64][64] row-major (in_f x out_f)
    const float* __restrict__ bias)      // [64]
{
    __shared__ float4 Wl[64][16];        // W[k][:] as 16 float4 -> Wl[k][l]
    __shared__ float4 bl[16];
    __shared__ float  s[4][4][68];       // [wave][row-sub][k], stride 68 -> conflict-free broadcast

    const int t = threadIdx.x;

    // Stage W (1024 float4) and bias (16 float4)
    for (int i = t; i < 64 * 16; i += 256)
        ((float4*)Wl)[i] = ((const float4*)W)[i];
    if (t < 16) bl[t] = ((const float4*)bias)[t];

    const int wid  = t >> 6;
    const int lane = t & 63;
    const int sub  = lane >> 4;
    const int l    = lane & 15;

    // 16 rows per block; wave wid owns rows base..base+3
    const long base = (long)blockIdx.x * 16 + wid * 4;

    // Cooperative load: 4 rows = 256 consecutive floats = 64 float4 (one per lane)
    float4 sv = *reinterpret_cast<const float4*>(io + base * FDIM + lane * 4);
    *reinterpret_cast<float4*>(&s[wid][lane >> 4][(lane & 15) * 4]) = sv;
    __syncthreads();

    float4 acc = {0.f, 0.f, 0.f, 0.f};
    const float* srow = s[wid][sub];
    #pragma unroll
    for (int k = 0; k < FDIM; ++k) {
        const float a = srow[k];           // broadcast within 16-lane group
        const float4 w = Wl[k][l];
        acc.x += a * w.x;
        acc.y += a * w.y;
        acc.z += a * w.z;
        acc.w += a * w.w;
    }
    const float4 b = bl[l];
    acc.x += b.x; acc.y += b.y; acc.z += b.z; acc.w += b.w;

    // Row L2 norm over the 16-lane subgroup
    float p = acc.x*acc.x + acc.y*acc.y + acc.z*acc.z + acc.w*acc.w;
    #pragma unroll
    for (int off = 1; off < 16; off <<= 1)
        p += __shfl_xor(p, off);
    const float inv = 1.0f / sqrtf(p);
    acc.x *= inv; acc.y *= inv; acc.z *= inv; acc.w *= inv;

    *reinterpret_cast<float4*>(io + (base + sub) * FDIM + l * 4) = acc;
}

extern "C" void kernel_launch(void* const* d_in, const int* in_sizes, int n_in,
                              void* d_out, int out_size, void* d_ws, size_t ws_size,
                              hipStream_t stream) {
    const float* x     = (const float*)d_in[0];
    const int*   erow  = (const int*)d_in[1];
    const int*   ecol  = (const int*)d_in[2];
    const float* eval  = (const float*)d_in[3];
    const float* W     = (const float*)d_in[4];
    const float* bias  = (const float*)d_in[5];
    float* out = (float*)d_out;

    const int n_edges = in_sizes[1];

    // support accumulates in d_out -> must start at zero every call
    hipMemsetAsync(out, 0, (size_t)N_NODES * FDIM * sizeof(float), stream);

    // SpMM: 16 lanes per edge -> n_edges*16 threads
    {
        long threads = (long)n_edges * 16;
        int grid = (int)((threads + 255) / 256);
        spmm_atomic<<<grid, 256, 0, stream>>>(x, erow, ecol, eval, out, n_edges);
    }

    // GEMM + bias + L2 normalize, in place (16 rows per block; N_NODES = 6250*16)
    {
        int grid = (N_NODES + 15) / 16;
        gemm_norm<<<grid, 256, 0, stream>>>(out, W, bias);
    }
}

// Round 5
// 292.781 us; speedup vs baseline: 4.7249x; 4.7249x over previous
//
#include <hip/hip_runtime.h>

#define N_NODES 100000
#define FDIM 64
#define CHUNK 1024
#define NCHUNK ((N_NODES + CHUNK - 1) / CHUNK)   // 98

// ---------------- ws layout ----------------
// cnt  : offset 0          N_NODES ints (counts -> start offsets -> end offsets)
// bsum : offset 512 KiB    NCHUNK ints
// cv   : offset 1 MiB      n_edges int2 {col, float_bits(val)}
#define WS_BSUM_OFF (512u * 1024u)
#define WS_CV_OFF   (1024u * 1024u)

// ============ fallback path (round-4, verified): fp32 HW atomics ============
__global__ __launch_bounds__(256) void spmm_atomic(
    const float* __restrict__ x, const int* __restrict__ erow,
    const int* __restrict__ ecol, const float* __restrict__ eval,
    float* __restrict__ out, int n_edges)
{
    int tid = blockIdx.x * 256 + threadIdx.x;
    int e = tid >> 4;
    int l = tid & 15;
    if (e >= n_edges) return;
    int row = erow[e], col = ecol[e];
    float v = eval[e];
    const float4 xv = *reinterpret_cast<const float4*>(x + (size_t)col * FDIM + l * 4);
    float* dst = out + (size_t)row * FDIM + l * 4;
    unsafeAtomicAdd(dst + 0, v * xv.x);
    unsafeAtomicAdd(dst + 1, v * xv.y);
    unsafeAtomicAdd(dst + 2, v * xv.z);
    unsafeAtomicAdd(dst + 3, v * xv.w);
}

// ============ CSR build ============
__global__ __launch_bounds__(256) void hist_rows(
    const int* __restrict__ erow, int* __restrict__ cnt, int n_edges)
{
    for (int e = blockIdx.x * 256 + threadIdx.x; e < n_edges; e += gridDim.x * 256)
        atomicAdd(&cnt[erow[e]], 1);
}

// per-chunk totals: bsum[b] = sum of cnt[b*1024 .. b*1024+1023]
__global__ __launch_bounds__(256) void chunk_sums(
    const int* __restrict__ cnt, int* __restrict__ bsum)
{
    __shared__ int sdata[256];
    const int b = blockIdx.x, t = threadIdx.x;
    int s = 0;
    #pragma unroll
    for (int k = 0; k < 4; ++k) {
        int idx = b * CHUNK + k * 256 + t;
        if (idx < N_NODES) s += cnt[idx];
    }
    sdata[t] = s;
    __syncthreads();
    for (int off = 128; off > 0; off >>= 1) {
        if (t < off) sdata[t] += sdata[t + off];
        __syncthreads();
    }
    if (t == 0) bsum[b] = sdata[0];
}

// exclusive scan of bsum (NCHUNK <= 128), one block of 128 threads
__global__ __launch_bounds__(128) void scan_bsum(int* __restrict__ bsum)
{
    __shared__ int sdata[128];
    const int t = threadIdx.x;
    int v0 = (t < NCHUNK) ? bsum[t] : 0;
    sdata[t] = v0;
    __syncthreads();
    for (int off = 1; off < 128; off <<= 1) {
        int v = (t >= off) ? sdata[t - off] : 0;
        __syncthreads();
        sdata[t] += v;
        __syncthreads();
    }
    if (t < NCHUNK) bsum[t] = sdata[t] - v0;   // exclusive
}

// rewrite cnt[i] := global exclusive prefix (start offset of row i)
__global__ __launch_bounds__(256) void chunk_scan(
    int* __restrict__ cnt, const int* __restrict__ bsum)
{
    __shared__ int sdata[256];
    const int b = blockIdx.x, t = threadIdx.x;
    const int base = b * CHUNK + t * 4;
    int c[4];
    int s = 0;
    #pragma unroll
    for (int j = 0; j < 4; ++j) {
        c[j] = (base + j < N_NODES) ? cnt[base + j] : 0;
        s += c[j];
    }
    sdata[t] = s;
    __syncthreads();
    for (int off = 1; off < 256; off <<= 1) {
        int v = (t >= off) ? sdata[t - off] : 0;
        __syncthreads();
        sdata[t] += v;
        __syncthreads();
    }
    int run = bsum[b] + sdata[t] - s;          // exclusive across threads
    #pragma unroll
    for (int j = 0; j < 4; ++j) {
        if (base + j < N_NODES) cnt[base + j] = run;
        run += c[j];
    }
}

// scatter edges into CSR order; afterwards cnt[r] == end offset of row r
__global__ __launch_bounds__(256) void scatter_edges(
    const int* __restrict__ erow, const int* __restrict__ ecol,
    const float* __restrict__ eval, int* __restrict__ cnt,
    int2* __restrict__ cv, int n_edges)
{
    for (int e = blockIdx.x * 256 + threadIdx.x; e < n_edges; e += gridDim.x * 256) {
        int r = erow[e];
        int pos = atomicAdd(&cnt[r], 1);
        cv[pos] = make_int2(ecol[e], __float_as_int(eval[e]));
    }
}

// ============ SpMM over CSR: one wave per row, no atomics ============
// 16-lane sub-groups x 4 edges in flight; lane l covers features [4l, 4l+4).
__global__ __launch_bounds__(256) void spmm_csr(
    const float* __restrict__ x, const int* __restrict__ endoff,
    const int2* __restrict__ cv, float* __restrict__ out)
{
    const int wave = (blockIdx.x * 256 + threadIdx.x) >> 6;
    if (wave >= N_NODES) return;
    const int lane = threadIdx.x & 63;
    const int sub = lane >> 4, l = lane & 15;
    const int r = wave;
    const int beg = (r == 0) ? 0 : endoff[r - 1];
    const int end = endoff[r];

    float4 acc = {0.f, 0.f, 0.f, 0.f};
    for (int it = beg + sub; it < end; it += 4) {
        const int2 e = cv[it];
        const float v = __int_as_float(e.y);
        const float4 xv = *reinterpret_cast<const float4*>(x + (size_t)e.x * FDIM + l * 4);
        acc.x += v * xv.x; acc.y += v * xv.y; acc.z += v * xv.z; acc.w += v * xv.w;
    }
    // reduce the 4 sub-groups (same row)
    #pragma unroll
    for (int off = 16; off < 64; off <<= 1) {
        acc.x += __shfl_xor(acc.x, off);
        acc.y += __shfl_xor(acc.y, off);
        acc.z += __shfl_xor(acc.z, off);
        acc.w += __shfl_xor(acc.w, off);
    }
    if (sub == 0)
        *reinterpret_cast<float4*>(out + (size_t)r * FDIM + l * 4) = acc;
}

// ============ GEMM + bias + L2 normalize (verified round-4) ============
__global__ __launch_bounds__(256) void gemm_norm(
    float* __restrict__ io, const float* __restrict__ W,
    const float* __restrict__ bias)
{
    __shared__ float4 Wl[64][16];
    __shared__ float4 bl[16];
    __shared__ float  s[4][4][68];

    const int t = threadIdx.x;
    for (int i = t; i < 64 * 16; i += 256)
        ((float4*)Wl)[i] = ((const float4*)W)[i];
    if (t < 16) bl[t] = ((const float4*)bias)[t];

    const int wid  = t >> 6;
    const int lane = t & 63;
    const int sub  = lane >> 4;
    const int l    = lane & 15;
    const long base = (long)blockIdx.x * 16 + wid * 4;

    float4 sv = *reinterpret_cast<const float4*>(io + base * FDIM + lane * 4);
    *reinterpret_cast<float4*>(&s[wid][lane >> 4][(lane & 15) * 4]) = sv;
    __syncthreads();

    float4 acc = {0.f, 0.f, 0.f, 0.f};
    const float* srow = s[wid][sub];
    #pragma unroll
    for (int k = 0; k < FDIM; ++k) {
        const float a = srow[k];
        const float4 w = Wl[k][l];
        acc.x += a * w.x; acc.y += a * w.y; acc.z += a * w.z; acc.w += a * w.w;
    }
    const float4 b = bl[l];
    acc.x += b.x; acc.y += b.y; acc.z += b.z; acc.w += b.w;

    float p = acc.x*acc.x + acc.y*acc.y + acc.z*acc.z + acc.w*acc.w;
    #pragma unroll
    for (int off = 1; off < 16; off <<= 1)
        p += __shfl_xor(p, off);
    const float inv = 1.0f / sqrtf(p);
    acc.x *= inv; acc.y *= inv; acc.z *= inv; acc.w *= inv;

    *reinterpret_cast<float4*>(io + (base + sub) * FDIM + l * 4) = acc;
}

extern "C" void kernel_launch(void* const* d_in, const int* in_sizes, int n_in,
                              void* d_out, int out_size, void* d_ws, size_t ws_size,
                              hipStream_t stream) {
    const float* x    = (const float*)d_in[0];
    const int*   erow = (const int*)d_in[1];
    const int*   ecol = (const int*)d_in[2];
    const float* eval = (const float*)d_in[3];
    const float* W    = (const float*)d_in[4];
    const float* bias = (const float*)d_in[5];
    float* out = (float*)d_out;
    const int n_edges = in_sizes[1];

    const size_t need = (size_t)WS_CV_OFF + (size_t)n_edges * sizeof(int2);

    if (ws_size >= need) {
        // -------- CSR path: no fp atomics --------
        int*  cnt  = (int*)d_ws;
        int*  bsum = (int*)((char*)d_ws + WS_BSUM_OFF);
        int2* cv   = (int2*)((char*)d_ws + WS_CV_OFF);

        hipMemsetAsync(cnt, 0, N_NODES * sizeof(int), stream);
        hist_rows<<<2048, 256, 0, stream>>>(erow, cnt, n_edges);
        chunk_sums<<<NCHUNK, 256, 0, stream>>>(cnt, bsum);
        scan_bsum<<<1, 128, 0, stream>>>(bsum);
        chunk_scan<<<NCHUNK, 256, 0, stream>>>(cnt, bsum);
        scatter_edges<<<2048, 256, 0, stream>>>(erow, ecol, eval, cnt, cv, n_edges);
        spmm_csr<<<(N_NODES + 3) / 4, 256, 0, stream>>>(x, cnt, cv, out);
    } else {
        // -------- fallback: verified atomic path --------
        hipMemsetAsync(out, 0, (size_t)N_NODES * FDIM * sizeof(float), stream);
        long threads = (long)n_edges * 16;
        spmm_atomic<<<(int)((threads + 255) / 256), 256, 0, stream>>>(
            x, erow, ecol, eval, out, n_edges);
    }

    gemm_norm<<<N_NODES / 16, 256, 0, stream>>>(out, W, bias);
}